// Round 4
// baseline (2227.727 us; speedup 1.0000x reference)
//
#include <hip/hip_runtime.h>

// Wav2Vec BLSTM: 4-layer bi-LSTM (B=32, T=1000, H=32, G=128) + mean-pool + fc.
//
// Round 4 (r3 + compile fix):
//  - h-broadcast via 32x ds_swizzle(or-broadcast) into VGPRs, pattern imm
//    supplied through a recursive template (ICE requirement).
//  - matvec as v_pk_fma_f32 (float2 + __builtin_elementwise_fma).
//  - -log2e (g-rows -2log2e) pre-folded into weights + GEMM epilogue.
//  - branch-free h store.

#define TB 1000
#define LOG2E 1.44269504088896340736f

typedef int   v2i __attribute__((ext_vector_type(2)));
typedef float v2f __attribute__((ext_vector_type(2)));

__device__ __forceinline__ float fexp2(float x) {
#if __has_builtin(__builtin_amdgcn_exp2f)
    return __builtin_amdgcn_exp2f(x);
#else
    return exp2f(x);
#endif
}

// returns v[lane ^ 32]; pickx precomputed per-lane (convention-independent)
__device__ __forceinline__ float lane_xor32(float v, bool pickx) {
    v2i r = __builtin_amdgcn_permlane32_swap(__float_as_int(v), __float_as_int(v),
                                             false, false);
    return __int_as_float(pickx ? r[0] : r[1]);
}

// broadcast h (int bits) from lanes 2Q,2Q+1 of each 32-half into hv[Q]
// ds_swizzle BitMode offset = (xor<<10)|(or<<5)|and ; and=0,or=k -> lane k
template<int Q>
__device__ __forceinline__ void bcast_h(int hb_, v2f* hv) {
    hv[Q][0] = __int_as_float(__builtin_amdgcn_ds_swizzle(hb_, (2 * Q + 0) << 5));
    hv[Q][1] = __int_as_float(__builtin_amdgcn_ds_swizzle(hb_, (2 * Q + 1) << 5));
    if constexpr (Q + 1 < 16) bcast_h<Q + 1>(hb_, hv);
}

// ---------------------------------------------------------------------------
// GEMM: A[32000][K] x W[256][K]^T + (bi+bh), then row-dependent prescale by
// -log2e (g-rows: -2log2e) -> xpT[2*32][128][1000] (dir=1 time-reversed).
// ---------------------------------------------------------------------------
__global__ __launch_bounds__(256)
void gemm_proj(const float* __restrict__ A, int K,
               const float* __restrict__ W,
               const float* __restrict__ bi,
               const float* __restrict__ bh,
               float* __restrict__ xpT)
{
    __shared__ __align__(16) float As[32][68];    // [k][m]
    __shared__ __align__(16) float Bs[32][132];   // [k][n]

    const int tid = threadIdx.x;
    const int m0 = blockIdx.x * 64;
    const int n0 = blockIdx.y * 128;
    const int tx = tid & 15;     // m-quad
    const int ty = tid >> 4;     // n-octet

    float acc[8][4];
#pragma unroll
    for (int i = 0; i < 8; ++i)
#pragma unroll
        for (int jj = 0; jj < 4; ++jj) acc[i][jj] = 0.0f;

    const int ar = tid >> 3;
    const int ak = (tid & 7) * 4;
    const int wr = tid >> 1;
    const int wk = (tid & 1) * 16;

    for (int k0 = 0; k0 < K; k0 += 32) {
        float4 a0 = *(const float4*)(A + (size_t)(m0 + ar) * K + k0 + ak);
        float4 a1 = *(const float4*)(A + (size_t)(m0 + ar + 32) * K + k0 + ak);
        const float* wp = W + (size_t)(n0 + wr) * K + k0 + wk;
        float4 w0 = *(const float4*)(wp + 0);
        float4 w1 = *(const float4*)(wp + 4);
        float4 w2 = *(const float4*)(wp + 8);
        float4 w3 = *(const float4*)(wp + 12);

        __syncthreads();
        As[ak + 0][ar] = a0.x; As[ak + 1][ar] = a0.y;
        As[ak + 2][ar] = a0.z; As[ak + 3][ar] = a0.w;
        As[ak + 0][ar + 32] = a1.x; As[ak + 1][ar + 32] = a1.y;
        As[ak + 2][ar + 32] = a1.z; As[ak + 3][ar + 32] = a1.w;
        {
            float wv[16] = {w0.x, w0.y, w0.z, w0.w,
                            w1.x, w1.y, w1.z, w1.w,
                            w2.x, w2.y, w2.z, w2.w,
                            w3.x, w3.y, w3.z, w3.w};
#pragma unroll
            for (int q = 0; q < 16; ++q) Bs[wk + q][wr] = wv[q];
        }
        __syncthreads();

#pragma unroll
        for (int kk = 0; kk < 32; ++kk) {
            float4 av = *(const float4*)&As[kk][tx * 4];
            float4 b0 = *(const float4*)&Bs[kk][ty * 8];
            float4 b1 = *(const float4*)&Bs[kk][ty * 8 + 4];
            float bn[8] = {b0.x, b0.y, b0.z, b0.w, b1.x, b1.y, b1.z, b1.w};
#pragma unroll
            for (int ni = 0; ni < 8; ++ni) {
                acc[ni][0] = fmaf(av.x, bn[ni], acc[ni][0]);
                acc[ni][1] = fmaf(av.y, bn[ni], acc[ni][1]);
                acc[ni][2] = fmaf(av.z, bn[ni], acc[ni][2]);
                acc[ni][3] = fmaf(av.w, bn[ni], acc[ni][3]);
            }
        }
    }

    const int dir = n0 >> 7;
    const int mbase = m0 + tx * 4;
    const int bidx = mbase / 1000;
    const int ttq = mbase - bidx * 1000;
#pragma unroll
    for (int ni = 0; ni < 8; ++ni) {
        const int n = n0 + ty * 8 + ni;
        const float bias = bi[n] + bh[n];
        const float sc = (((n >> 5) & 3) == 2) ? (-2.0f * LOG2E) : (-LOG2E);
        float* row = xpT + ((size_t)((dir * 32 + bidx) * 128) + (n & 127)) * TB;
        if (dir == 0) {
            float4 o = {(acc[ni][0] + bias) * sc, (acc[ni][1] + bias) * sc,
                        (acc[ni][2] + bias) * sc, (acc[ni][3] + bias) * sc};
            *(float4*)(row + ttq) = o;
        } else {
            float4 o = {(acc[ni][3] + bias) * sc, (acc[ni][2] + bias) * sc,
                        (acc[ni][1] + bias) * sc, (acc[ni][0] + bias) * sc};
            *(float4*)(row + (TB - 4 - ttq)) = o;
        }
    }
}

// ---------------------------------------------------------------------------
// Recurrence: one wave per (dir,b). Lane l owns gate rows r0=(l&31)+(l>=32?64:0)
// and r1=r0+32 (i/f on lanes<32, g/o on lanes>=32, both halves redundant).
// h broadcast via ds_swizzle; half-exchange via permlane32_swap.
// Gates arrive prescaled by -log2e (g-rows -2log2e): exp2 direct.
// ---------------------------------------------------------------------------
template<int MODE>
__global__ __launch_bounds__(64)
void lstm_rec(const float* __restrict__ xpT,  // [64][128][1000] prescaled
              const float* __restrict__ whh,  // [2][128][32]
              float* __restrict__ hout,       // [32][1000][64]
              float* __restrict__ hsum)       // [32][64]
{
    const int blk  = blockIdx.x;   // dir*32 + b
    const int dir  = blk >> 5;
    const int b    = blk & 31;
    const int lane = threadIdx.x & 63;
    const int j    = lane & 31;
    const int up   = lane >> 5;
    const int r0   = j + up * 64;
    const int r1   = r0 + 32;

    v2i det = __builtin_amdgcn_permlane32_swap(lane, lane, false, false);
    const bool pickx = (det[0] == (lane ^ 32));

    // recurrent weights, packed float2, prescaled
    const float sA = up ? (-2.0f * LOG2E) : (-LOG2E);
    const float sB = -LOG2E;
    v2f wa[16], wb[16];
    {
        const float* wp0 = whh + (size_t)(dir * 128 + r0) * 32;
        const float* wp1 = whh + (size_t)(dir * 128 + r1) * 32;
#pragma unroll
        for (int q = 0; q < 8; ++q) {
            float4 v = *(const float4*)(wp0 + q * 4);
            wa[2 * q + 0][0] = v.x * sA; wa[2 * q + 0][1] = v.y * sA;
            wa[2 * q + 1][0] = v.z * sA; wa[2 * q + 1][1] = v.w * sA;
            float4 u = *(const float4*)(wp1 + q * 4);
            wb[2 * q + 0][0] = u.x * sB; wb[2 * q + 0][1] = u.y * sB;
            wb[2 * q + 1][0] = u.z * sB; wb[2 * q + 1][1] = u.w * sB;
        }
    }

    const float* pa = xpT + ((size_t)blk * 128 + r0) * TB;
    const float* pb = xpT + ((size_t)blk * 128 + r1) * TB;

    float4 A0 = *(const float4*)(pa + 0);
    float4 B0 = *(const float4*)(pb + 0);
    float4 A1 = *(const float4*)(pa + 4);
    float4 B1 = *(const float4*)(pb + 4);

    const float mA = up ?  2.0f : 1.0f;
    const float mB = up ? -1.0f : 0.0f;

    float c = 0.0f, h = 0.0f, hacc = 0.0f;
    float* hq = hout + ((size_t)b * TB + (dir ? TB - 1 : 0)) * 64 + dir * 32 + j;
    const int hstep = dir ? -64 : 64;

#define LSTM_STEP(GA, GB) do {                                                  \
        v2f hv[16];                                                             \
        bcast_h<0>(__float_as_int(h), hv);                                      \
        v2f qa0 = {(GA), 0.0f}, qa1 = {0.f,0.f}, qa2 = {0.f,0.f}, qa3 = {0.f,0.f}; \
        v2f qb0 = {(GB), 0.0f}, qb1 = {0.f,0.f}, qb2 = {0.f,0.f}, qb3 = {0.f,0.f}; \
        _Pragma("unroll")                                                       \
        for (int q = 0; q < 4; ++q) {                                           \
            qa0 = __builtin_elementwise_fma(hv[4*q+0], wa[4*q+0], qa0);         \
            qb0 = __builtin_elementwise_fma(hv[4*q+0], wb[4*q+0], qb0);         \
            qa1 = __builtin_elementwise_fma(hv[4*q+1], wa[4*q+1], qa1);         \
            qb1 = __builtin_elementwise_fma(hv[4*q+1], wb[4*q+1], qb1);         \
            qa2 = __builtin_elementwise_fma(hv[4*q+2], wa[4*q+2], qa2);         \
            qb2 = __builtin_elementwise_fma(hv[4*q+2], wb[4*q+2], qb2);         \
            qa3 = __builtin_elementwise_fma(hv[4*q+3], wa[4*q+3], qa3);         \
            qb3 = __builtin_elementwise_fma(hv[4*q+3], wb[4*q+3], qb3);         \
        }                                                                       \
        v2f sa = (qa0 + qa1) + (qa2 + qa3);                                     \
        v2f sb = (qb0 + qb1) + (qb2 + qb3);                                     \
        float g0 = sa[0] + sa[1];                                               \
        float g1 = sb[0] + sb[1];                                               \
        float s0 = __builtin_amdgcn_rcpf(1.0f + fexp2(g0));                     \
        float v0 = fmaf(mA, s0, mB);   /* lo: sig(i); hi: tanh(g) */            \
        float v1 = __builtin_amdgcn_rcpf(1.0f + fexp2(g1)); /* sig(f)/sig(o) */ \
        float o0 = lane_xor32(v0, pickx);                                       \
        float o1 = lane_xor32(v1, pickx);                                       \
        float si = up ? o0 : v0;                                                \
        float sf = up ? o1 : v1;                                                \
        float tg = up ? v0 : o0;                                                \
        float so = up ? v1 : o1;                                                \
        c = fmaf(sf, c, si * tg);                                               \
        float tc = fmaf(2.0f, __builtin_amdgcn_rcpf(1.0f + fexp2(c * (-2.0f * LOG2E))), -1.0f); \
        h = so * tc;                                                            \
        if (MODE == 0) *hq = h; else hacc += h;                                 \
        hq += hstep;                                                            \
    } while (0)

    for (int it = 0; it < 125; ++it) {
        const int base = it * 8;
        const int offn0 = min(base + 8,  TB - 4);   // clamped, unconditional
        const int offn1 = min(base + 12, TB - 4);
        float4 NA0 = *(const float4*)(pa + offn0);
        float4 NB0 = *(const float4*)(pb + offn0);
        float4 NA1 = *(const float4*)(pa + offn1);
        float4 NB1 = *(const float4*)(pb + offn1);

        LSTM_STEP(A0.x, B0.x);
        LSTM_STEP(A0.y, B0.y);
        LSTM_STEP(A0.z, B0.z);
        LSTM_STEP(A0.w, B0.w);
        LSTM_STEP(A1.x, B1.x);
        LSTM_STEP(A1.y, B1.y);
        LSTM_STEP(A1.z, B1.z);
        LSTM_STEP(A1.w, B1.w);

        A0 = NA0; B0 = NB0; A1 = NA1; B1 = NB1;
    }
#undef LSTM_STEP

    if (MODE == 1) hsum[b * 64 + dir * 32 + j] = hacc;
}

// ---------------------------------------------------------------------------
__global__ __launch_bounds__(64)
void final_fc(const float* __restrict__ hsum,
              const float* __restrict__ fcw,
              const float* __restrict__ fcb,
               float* __restrict__ out)
{
    int b = blockIdx.x;
    int l = threadIdx.x;
    float v = hsum[b * 64 + l] * (1.0f / (float)TB) * fcw[l];
#pragma unroll
    for (int off = 32; off > 0; off >>= 1)
        v += __shfl_down(v, off, 64);
    if (l == 0) out[b] = v + fcb[0];
}

// ---------------------------------------------------------------------------
extern "C" void kernel_launch(void* const* d_in, const int* in_sizes, int n_in,
                              void* d_out, int out_size, void* d_ws, size_t ws_size,
                              hipStream_t stream)
{
    const float* x    = (const float*)d_in[0];
    const float* wih0 = (const float*)d_in[1];
    const float* whh0 = (const float*)d_in[2];
    const float* bih0 = (const float*)d_in[3];
    const float* bhh0 = (const float*)d_in[4];
    const float* wih  = (const float*)d_in[5];
    const float* whh  = (const float*)d_in[6];
    const float* bih  = (const float*)d_in[7];
    const float* bhh  = (const float*)d_in[8];
    const float* fcw  = (const float*)d_in[9];
    const float* fcb  = (const float*)d_in[10];
    float* out = (float*)d_out;

    float* ws = (float*)d_ws;
    float* xp = ws;                         // 64*128*1000 floats
    float* hb = ws + 8192000;               // 32*1000*64 floats
    float* hs = ws + 8192000 + 2048000;     // 32*64

    dim3 gb(500, 2);

    gemm_proj<<<gb, 256, 0, stream>>>(x, 1024, wih0, bih0, bhh0, xp);
    lstm_rec<0><<<64, 64, 0, stream>>>(xp, whh0, hb, hs);

    for (int l = 1; l < 4; ++l) {
        const float* wl  = wih + (size_t)(l - 1) * 2 * 128 * 64;
        const float* whl = whh + (size_t)(l - 1) * 2 * 128 * 32;
        const float* b1  = bih + (size_t)(l - 1) * 256;
        const float* b2  = bhh + (size_t)(l - 1) * 256;
        gemm_proj<<<gb, 256, 0, stream>>>(hb, 64, wl, b1, b2, xp);
        if (l == 3) lstm_rec<1><<<64, 64, 0, stream>>>(xp, whl, hb, hs);
        else        lstm_rec<0><<<64, 64, 0, stream>>>(xp, whl, hb, hs);
    }

    final_fc<<<32, 64, 0, stream>>>(hs, fcw, fcb, out);
}

// Round 5
// 1211.909 us; speedup vs baseline: 1.8382x; 1.8382x over previous
//
#include <hip/hip_runtime.h>

// Wav2Vec BLSTM: 4-layer bi-LSTM (B=32, T=1000, H=32, G=128) + mean-pool + fc.
//
// Round 5 (revert r4's ds_swizzle; r2 readlane skeleton + improvements):
//  - h-broadcast via v_readlane, BATCHED 8-at-a-time into u64 SGPR pairs
//    (amortizes VALU->SGPR->VALU wait states).
//  - matvec via inline-asm v_pk_fma_f32: sgpr-pair broadcast x vgpr-pair
//    weights (64 scalar fma -> 32 pk_fma).
//  - -log2e (g-rows -2log2e) pre-folded into weights + GEMM epilogue so
//    gates feed v_exp_f32 directly (verified in r4).
//  - branch-free h store; xpT transposed/time-reversed streams (r2).

#define TB 1000
#define LOG2E 1.44269504088896340736f

typedef int   v2i __attribute__((ext_vector_type(2)));
typedef float v2f __attribute__((ext_vector_type(2)));

__device__ __forceinline__ float fexp2(float x) {
#if __has_builtin(__builtin_amdgcn_exp2f)
    return __builtin_amdgcn_exp2f(x);
#else
    return exp2f(x);
#endif
}

// returns v[lane ^ 32]; pickx precomputed per-lane (convention-independent)
__device__ __forceinline__ float lane_xor32(float v, bool pickx) {
    v2i r = __builtin_amdgcn_permlane32_swap(__float_as_int(v), __float_as_int(v),
                                             false, false);
    return __int_as_float(pickx ? r[0] : r[1]);
}

__device__ __forceinline__ void pk_fma(v2f& acc, uint64_t s2, v2f w2) {
    asm("v_pk_fma_f32 %0, %1, %2, %0" : "+v"(acc) : "s"(s2), "v"(w2));
}

// ---------------------------------------------------------------------------
// GEMM: A[32000][K] x W[256][K]^T + (bi+bh), then row-dependent prescale by
// -log2e (g-rows: -2log2e) -> xpT[2*32][128][1000] (dir=1 time-reversed).
// ---------------------------------------------------------------------------
__global__ __launch_bounds__(256)
void gemm_proj(const float* __restrict__ A, int K,
               const float* __restrict__ W,
               const float* __restrict__ bi,
               const float* __restrict__ bh,
               float* __restrict__ xpT)
{
    __shared__ __align__(16) float As[32][68];    // [k][m]
    __shared__ __align__(16) float Bs[32][132];   // [k][n]

    const int tid = threadIdx.x;
    const int m0 = blockIdx.x * 64;
    const int n0 = blockIdx.y * 128;
    const int tx = tid & 15;     // m-quad
    const int ty = tid >> 4;     // n-octet

    float acc[8][4];
#pragma unroll
    for (int i = 0; i < 8; ++i)
#pragma unroll
        for (int jj = 0; jj < 4; ++jj) acc[i][jj] = 0.0f;

    const int ar = tid >> 3;
    const int ak = (tid & 7) * 4;
    const int wr = tid >> 1;
    const int wk = (tid & 1) * 16;

    for (int k0 = 0; k0 < K; k0 += 32) {
        float4 a0 = *(const float4*)(A + (size_t)(m0 + ar) * K + k0 + ak);
        float4 a1 = *(const float4*)(A + (size_t)(m0 + ar + 32) * K + k0 + ak);
        const float* wp = W + (size_t)(n0 + wr) * K + k0 + wk;
        float4 w0 = *(const float4*)(wp + 0);
        float4 w1 = *(const float4*)(wp + 4);
        float4 w2 = *(const float4*)(wp + 8);
        float4 w3 = *(const float4*)(wp + 12);

        __syncthreads();
        As[ak + 0][ar] = a0.x; As[ak + 1][ar] = a0.y;
        As[ak + 2][ar] = a0.z; As[ak + 3][ar] = a0.w;
        As[ak + 0][ar + 32] = a1.x; As[ak + 1][ar + 32] = a1.y;
        As[ak + 2][ar + 32] = a1.z; As[ak + 3][ar + 32] = a1.w;
        {
            float wv[16] = {w0.x, w0.y, w0.z, w0.w,
                            w1.x, w1.y, w1.z, w1.w,
                            w2.x, w2.y, w2.z, w2.w,
                            w3.x, w3.y, w3.z, w3.w};
#pragma unroll
            for (int q = 0; q < 16; ++q) Bs[wk + q][wr] = wv[q];
        }
        __syncthreads();

#pragma unroll
        for (int kk = 0; kk < 32; ++kk) {
            float4 av = *(const float4*)&As[kk][tx * 4];
            float4 b0 = *(const float4*)&Bs[kk][ty * 8];
            float4 b1 = *(const float4*)&Bs[kk][ty * 8 + 4];
            float bn[8] = {b0.x, b0.y, b0.z, b0.w, b1.x, b1.y, b1.z, b1.w};
#pragma unroll
            for (int ni = 0; ni < 8; ++ni) {
                acc[ni][0] = fmaf(av.x, bn[ni], acc[ni][0]);
                acc[ni][1] = fmaf(av.y, bn[ni], acc[ni][1]);
                acc[ni][2] = fmaf(av.z, bn[ni], acc[ni][2]);
                acc[ni][3] = fmaf(av.w, bn[ni], acc[ni][3]);
            }
        }
    }

    const int dir = n0 >> 7;
    const int mbase = m0 + tx * 4;
    const int bidx = mbase / 1000;
    const int ttq = mbase - bidx * 1000;
#pragma unroll
    for (int ni = 0; ni < 8; ++ni) {
        const int n = n0 + ty * 8 + ni;
        const float bias = bi[n] + bh[n];
        const float sc = (((n >> 5) & 3) == 2) ? (-2.0f * LOG2E) : (-LOG2E);
        float* row = xpT + ((size_t)((dir * 32 + bidx) * 128) + (n & 127)) * TB;
        if (dir == 0) {
            float4 o = {(acc[ni][0] + bias) * sc, (acc[ni][1] + bias) * sc,
                        (acc[ni][2] + bias) * sc, (acc[ni][3] + bias) * sc};
            *(float4*)(row + ttq) = o;
        } else {
            float4 o = {(acc[ni][3] + bias) * sc, (acc[ni][2] + bias) * sc,
                        (acc[ni][1] + bias) * sc, (acc[ni][0] + bias) * sc};
            *(float4*)(row + (TB - 4 - ttq)) = o;
        }
    }
}

// ---------------------------------------------------------------------------
// Recurrence: one wave per (dir,b). Lane l owns gate rows r0=(l&31)+(l>=32?64:0)
// and r1=r0+32 (i/f on lanes<32, g/o on lanes>=32, both halves redundant).
// h broadcast via batched v_readlane -> sgpr pairs; matvec via v_pk_fma_f32;
// half-exchange via permlane32_swap. Gates arrive prescaled (exp2 direct).
// ---------------------------------------------------------------------------
template<int MODE>
__global__ __launch_bounds__(64)
void lstm_rec(const float* __restrict__ xpT,  // [64][128][1000] prescaled
              const float* __restrict__ whh,  // [2][128][32]
              float* __restrict__ hout,       // [32][1000][64]
              float* __restrict__ hsum)       // [32][64]
{
    const int blk  = blockIdx.x;   // dir*32 + b
    const int dir  = blk >> 5;
    const int b    = blk & 31;
    const int lane = threadIdx.x & 63;
    const int j    = lane & 31;
    const int up   = lane >> 5;
    const int r0   = j + up * 64;
    const int r1   = r0 + 32;

    v2i det = __builtin_amdgcn_permlane32_swap(lane, lane, false, false);
    const bool pickx = (det[0] == (lane ^ 32));

    // recurrent weights, packed float2, prescaled: wa[i] = w[2i..2i+1]
    const float sA = up ? (-2.0f * LOG2E) : (-LOG2E);
    const float sB = -LOG2E;
    v2f wa[16], wb[16];
    {
        const float* wp0 = whh + (size_t)(dir * 128 + r0) * 32;
        const float* wp1 = whh + (size_t)(dir * 128 + r1) * 32;
#pragma unroll
        for (int q = 0; q < 8; ++q) {
            float4 v = *(const float4*)(wp0 + q * 4);
            wa[2 * q + 0][0] = v.x * sA; wa[2 * q + 0][1] = v.y * sA;
            wa[2 * q + 1][0] = v.z * sA; wa[2 * q + 1][1] = v.w * sA;
            float4 u = *(const float4*)(wp1 + q * 4);
            wb[2 * q + 0][0] = u.x * sB; wb[2 * q + 0][1] = u.y * sB;
            wb[2 * q + 1][0] = u.z * sB; wb[2 * q + 1][1] = u.w * sB;
        }
    }

    const float* pa = xpT + ((size_t)blk * 128 + r0) * TB;
    const float* pb = xpT + ((size_t)blk * 128 + r1) * TB;

    float4 A0 = *(const float4*)(pa + 0);
    float4 B0 = *(const float4*)(pb + 0);
    float4 A1 = *(const float4*)(pa + 4);
    float4 B1 = *(const float4*)(pb + 4);

    const float mA = up ?  2.0f : 1.0f;
    const float mB = up ? -1.0f : 0.0f;

    float c = 0.0f, h = 0.0f, hacc = 0.0f;
    float* hq = hout + ((size_t)b * TB + (dir ? TB - 1 : 0)) * 64 + dir * 32 + j;
    const int hstep = dir ? -64 : 64;

#define LSTM_STEP(GA, GB) do {                                                  \
        const int hbits = __float_as_int(h);                                    \
        v2f qa0 = {(GA), 0.0f}, qa1 = {0.f,0.f}, qa2 = {0.f,0.f}, qa3 = {0.f,0.f}; \
        v2f qb0 = {(GB), 0.0f}, qb1 = {0.f,0.f}, qb2 = {0.f,0.f}, qb3 = {0.f,0.f}; \
        _Pragma("unroll")                                                       \
        for (int q = 0; q < 4; ++q) {  /* k = 8q .. 8q+7 */                     \
            uint32_t t0 = (uint32_t)__builtin_amdgcn_readlane(hbits, 8*q + 0);  \
            uint32_t t1 = (uint32_t)__builtin_amdgcn_readlane(hbits, 8*q + 1);  \
            uint32_t t2 = (uint32_t)__builtin_amdgcn_readlane(hbits, 8*q + 2);  \
            uint32_t t3 = (uint32_t)__builtin_amdgcn_readlane(hbits, 8*q + 3);  \
            uint32_t t4 = (uint32_t)__builtin_amdgcn_readlane(hbits, 8*q + 4);  \
            uint32_t t5 = (uint32_t)__builtin_amdgcn_readlane(hbits, 8*q + 5);  \
            uint32_t t6 = (uint32_t)__builtin_amdgcn_readlane(hbits, 8*q + 6);  \
            uint32_t t7 = (uint32_t)__builtin_amdgcn_readlane(hbits, 8*q + 7);  \
            uint64_t p01 = (uint64_t)t0 | ((uint64_t)t1 << 32);                 \
            uint64_t p23 = (uint64_t)t2 | ((uint64_t)t3 << 32);                 \
            uint64_t p45 = (uint64_t)t4 | ((uint64_t)t5 << 32);                 \
            uint64_t p67 = (uint64_t)t6 | ((uint64_t)t7 << 32);                 \
            pk_fma(qa0, p01, wa[4*q + 0]);                                      \
            pk_fma(qb0, p01, wb[4*q + 0]);                                      \
            pk_fma(qa1, p23, wa[4*q + 1]);                                      \
            pk_fma(qb1, p23, wb[4*q + 1]);                                      \
            pk_fma(qa2, p45, wa[4*q + 2]);                                      \
            pk_fma(qb2, p45, wb[4*q + 2]);                                      \
            pk_fma(qa3, p67, wa[4*q + 3]);                                      \
            pk_fma(qb3, p67, wb[4*q + 3]);                                      \
        }                                                                       \
        v2f sa = (qa0 + qa1) + (qa2 + qa3);                                     \
        v2f sb = (qb0 + qb1) + (qb2 + qb3);                                     \
        float g0 = sa[0] + sa[1];                                               \
        float g1 = sb[0] + sb[1];                                               \
        float s0 = __builtin_amdgcn_rcpf(1.0f + fexp2(g0));                     \
        float v0 = fmaf(mA, s0, mB);   /* lo: sig(i); hi: tanh(g) */            \
        float v1 = __builtin_amdgcn_rcpf(1.0f + fexp2(g1)); /* sig(f)/sig(o) */ \
        float o0 = lane_xor32(v0, pickx);                                       \
        float o1 = lane_xor32(v1, pickx);                                       \
        float si = up ? o0 : v0;                                                \
        float sf = up ? o1 : v1;                                                \
        float tg = up ? v0 : o0;                                                \
        float so = up ? v1 : o1;                                                \
        c = fmaf(sf, c, si * tg);                                               \
        float tc = fmaf(2.0f, __builtin_amdgcn_rcpf(1.0f + fexp2(c * (-2.0f * LOG2E))), -1.0f); \
        h = so * tc;                                                            \
        if (MODE == 0) *hq = h; else hacc += h;                                 \
        hq += hstep;                                                            \
    } while (0)

    for (int it = 0; it < 125; ++it) {
        const int base = it * 8;
        const int offn0 = min(base + 8,  TB - 4);   // clamped, unconditional
        const int offn1 = min(base + 12, TB - 4);
        float4 NA0 = *(const float4*)(pa + offn0);
        float4 NB0 = *(const float4*)(pb + offn0);
        float4 NA1 = *(const float4*)(pa + offn1);
        float4 NB1 = *(const float4*)(pb + offn1);

        LSTM_STEP(A0.x, B0.x);
        LSTM_STEP(A0.y, B0.y);
        LSTM_STEP(A0.z, B0.z);
        LSTM_STEP(A0.w, B0.w);
        LSTM_STEP(A1.x, B1.x);
        LSTM_STEP(A1.y, B1.y);
        LSTM_STEP(A1.z, B1.z);
        LSTM_STEP(A1.w, B1.w);

        A0 = NA0; B0 = NB0; A1 = NA1; B1 = NB1;
    }
#undef LSTM_STEP

    if (MODE == 1) hsum[b * 64 + dir * 32 + j] = hacc;
}

// ---------------------------------------------------------------------------
__global__ __launch_bounds__(64)
void final_fc(const float* __restrict__ hsum,
              const float* __restrict__ fcw,
              const float* __restrict__ fcb,
              float* __restrict__ out)
{
    int b = blockIdx.x;
    int l = threadIdx.x;
    float v = hsum[b * 64 + l] * (1.0f / (float)TB) * fcw[l];
#pragma unroll
    for (int off = 32; off > 0; off >>= 1)
        v += __shfl_down(v, off, 64);
    if (l == 0) out[b] = v + fcb[0];
}

// ---------------------------------------------------------------------------
extern "C" void kernel_launch(void* const* d_in, const int* in_sizes, int n_in,
                              void* d_out, int out_size, void* d_ws, size_t ws_size,
                              hipStream_t stream)
{
    const float* x    = (const float*)d_in[0];
    const float* wih0 = (const float*)d_in[1];
    const float* whh0 = (const float*)d_in[2];
    const float* bih0 = (const float*)d_in[3];
    const float* bhh0 = (const float*)d_in[4];
    const float* wih  = (const float*)d_in[5];
    const float* whh  = (const float*)d_in[6];
    const float* bih  = (const float*)d_in[7];
    const float* bhh  = (const float*)d_in[8];
    const float* fcw  = (const float*)d_in[9];
    const float* fcb  = (const float*)d_in[10];
    float* out = (float*)d_out;

    float* ws = (float*)d_ws;
    float* xp = ws;                         // 64*128*1000 floats
    float* hb = ws + 8192000;               // 32*1000*64 floats
    float* hs = ws + 8192000 + 2048000;     // 32*64

    dim3 gb(500, 2);

    gemm_proj<<<gb, 256, 0, stream>>>(x, 1024, wih0, bih0, bhh0, xp);
    lstm_rec<0><<<64, 64, 0, stream>>>(xp, whh0, hb, hs);

    for (int l = 1; l < 4; ++l) {
        const float* wl  = wih + (size_t)(l - 1) * 2 * 128 * 64;
        const float* whl = whh + (size_t)(l - 1) * 2 * 128 * 32;
        const float* b1  = bih + (size_t)(l - 1) * 256;
        const float* b2  = bhh + (size_t)(l - 1) * 256;
        gemm_proj<<<gb, 256, 0, stream>>>(hb, 64, wl, b1, b2, xp);
        if (l == 3) lstm_rec<1><<<64, 64, 0, stream>>>(xp, whl, hb, hs);
        else        lstm_rec<0><<<64, 64, 0, stream>>>(xp, whl, hb, hs);
    }

    final_fc<<<32, 64, 0, stream>>>(hs, fcw, fcb, out);
}